// Round 4
// baseline (56.889 us; speedup 1.0000x reference)
//
#include <hip/hip_runtime.h>
#include <math.h>

typedef float f32x2 __attribute__((ext_vector_type(2)));

#define K1_THREADS 256
#define R_OUTER    8
#define TILE       (K1_THREADS * R_OUTER)   // 2048 outer points per block
#define MAX_STAGE  1024                     // inner points staged per pass (12 KB LDS)

__device__ __forceinline__ f32x2 pk_fma(f32x2 a, f32x2 b, f32x2 c) {
    f32x2 d;
    asm("v_pk_fma_f32 %0, %1, %2, %3" : "=v"(d) : "v"(a), "v"(b), "v"(c));
    return d;
}
__device__ __forceinline__ float min3f(float a, float b, float c) {
    float d;
    asm("v_min3_f32 %0, %1, %2, %3" : "=v"(d) : "v"(a), "v"(b), "v"(c));
    return d;
}

// min_j |p - q_j|^2 = |p|^2 + min_j (c_j + a_j*px + b_j*py),
// a = -2 qx, b = -2 qy, c = qx^2 + qy^2   (a,b,c staged in LDS SoA)
__global__ __launch_bounds__(K1_THREADS, 4) void chamfer_partial_min(
    const float2* __restrict__ p, int n_p,
    const float2* __restrict__ q, int n_q,
    int nsplit, float* __restrict__ ws_min)
{
    const int side = blockIdx.z;
    const float2* __restrict__ outer = side ? q : p;
    const float2* __restrict__ inner = side ? p : q;
    const int n_outer = side ? n_q : n_p;
    const int n_inner = side ? n_p : n_q;
    const int total   = n_p + n_q;
    // ws layout: [split][global point] (coalesced writes + coalesced reduce reads)
    float* __restrict__ wbase =
        ws_min + (size_t)blockIdx.y * total + (side ? n_p : 0);

    const int tile = blockIdx.x;
    if (tile * TILE >= n_outer) return;          // uniform whole-block OOB
    const int split = blockIdx.y;
    const int tid   = threadIdx.x;

    // this split's inner range (chunk multiple of 4; splits may overlap-pad)
    const int chunk = ((n_inner + nsplit - 1) / nsplit + 3) & ~3;
    const int jlo   = split * chunk;

    // load R_OUTER outer points into registers
    int   idx[R_OUTER];
    f32x2 px2[R_OUTER], py2[R_OUTER];
    float hp[R_OUTER], m0[R_OUTER], m1[R_OUTER];
    #pragma unroll
    for (int r = 0; r < R_OUTER; ++r) {
        idx[r] = tile * TILE + r * K1_THREADS + tid;
        float2 pp = (idx[r] < n_outer) ? outer[idx[r]] : make_float2(0.f, 0.f);
        px2[r] = (f32x2){pp.x, pp.x};
        py2[r] = (f32x2){pp.y, pp.y};
        hp[r]  = fmaf(pp.x, pp.x, pp.y * pp.y);
        m0[r]  = 3.0e38f;
        m1[r]  = 3.0e38f;
    }

    __shared__ __align__(16) float sA[MAX_STAGE];
    __shared__ __align__(16) float sB[MAX_STAGE];
    __shared__ __align__(16) float sC[MAX_STAGE];

    for (int base = jlo; base < jlo + chunk; base += MAX_STAGE) {
        const int len = min(MAX_STAGE, jlo + chunk - base);   // multiple of 4

        // stage: 2 points per thread-iteration, float2 LDS writes
        for (int k = tid; k < (len >> 1); k += K1_THREADS) {
            const int pt = base + (k << 1);
            float x0, y0, x1, y1; int v0, v1;
            if (pt + 1 < n_inner) {
                float4 v = *(const float4*)&inner[pt];
                x0 = v.x; y0 = v.y; x1 = v.z; y1 = v.w; v0 = v1 = 1;
            } else if (pt < n_inner) {
                float2 a = inner[pt];
                x0 = a.x; y0 = a.y; x1 = 0.f; y1 = 0.f; v0 = 1; v1 = 0;
            } else {
                x0 = y0 = x1 = y1 = 0.f; v0 = v1 = 0;
            }
            *(float2*)&sA[k << 1] = make_float2(-2.f * x0, -2.f * x1);
            *(float2*)&sB[k << 1] = make_float2(-2.f * y0, -2.f * y1);
            *(float2*)&sC[k << 1] = make_float2(
                v0 ? fmaf(x0, x0, y0 * y0) : 3.0e37f,
                v1 ? fmaf(x1, x1, y1 * y1) : 3.0e37f);
        }
        __syncthreads();

        const int n4 = len >> 2;
        #pragma unroll 2
        for (int k4 = 0; k4 < n4; ++k4) {
            float4 A = ((const float4*)sA)[k4];
            float4 B = ((const float4*)sB)[k4];
            float4 C = ((const float4*)sC)[k4];
            f32x2 alo = (f32x2){A.x, A.y}, ahi = (f32x2){A.z, A.w};
            f32x2 blo = (f32x2){B.x, B.y}, bhi = (f32x2){B.z, B.w};
            f32x2 clo = (f32x2){C.x, C.y}, chi = (f32x2){C.z, C.w};
            #pragma unroll
            for (int r = 0; r < R_OUTER; ++r) {
                f32x2 t0 = pk_fma(blo, py2[r], clo);
                t0 = pk_fma(alo, px2[r], t0);
                f32x2 t1 = pk_fma(bhi, py2[r], chi);
                t1 = pk_fma(ahi, px2[r], t1);
                m0[r] = min3f(m0[r], t0.x, t0.y);
                m1[r] = min3f(m1[r], t1.x, t1.y);
            }
        }
        __syncthreads();
    }

    #pragma unroll
    for (int r = 0; r < R_OUTER; ++r)
        if (idx[r] < n_outer)
            wbase[idx[r]] = fminf(m0[r], m1[r]) + hp[r];
}

// fold nsplit partial mins per point (ws layout [split][point]), sqrt, sum per block
__global__ __launch_bounds__(256) void chamfer_reduce_points(
    const float* __restrict__ ws_min, int total_pts, int nsplit,
    float* __restrict__ block_sums)
{
    const int i = blockIdx.x * 256 + threadIdx.x;
    float d = 0.f;
    if (i < total_pts) {
        float mv = 3.0e38f;
        for (int j = 0; j < nsplit; ++j)
            mv = fminf(mv, ws_min[(size_t)j * total_pts + i]);
        d = sqrtf(fmaxf(mv, 0.f));
    }
    #pragma unroll
    for (int off = 32; off > 0; off >>= 1) d += __shfl_down(d, off);
    __shared__ float s[4];
    if ((threadIdx.x & 63) == 0) s[threadIdx.x >> 6] = d;
    __syncthreads();
    if (threadIdx.x == 0) block_sums[blockIdx.x] = (s[0] + s[1]) + (s[2] + s[3]);
}

__global__ __launch_bounds__(256) void chamfer_final(
    const float* __restrict__ block_sums, int n, float* __restrict__ out)
{
    float d = 0.f;
    for (int k = threadIdx.x; k < n; k += 256) d += block_sums[k];
    #pragma unroll
    for (int off = 32; off > 0; off >>= 1) d += __shfl_down(d, off);
    __shared__ float s[4];
    if ((threadIdx.x & 63) == 0) s[threadIdx.x >> 6] = d;
    __syncthreads();
    if (threadIdx.x == 0) out[0] = (s[0] + s[1]) + (s[2] + s[3]);
}

extern "C" void kernel_launch(void* const* d_in, const int* in_sizes, int n_in,
                              void* d_out, int out_size, void* d_ws, size_t ws_size,
                              hipStream_t stream) {
    const float2* p = (const float2*)d_in[0];   // (16384, 2) f32
    const float2* q = (const float2*)d_in[1];   // (16384, 2) f32
    const int N = in_sizes[0] / 2;
    const int M = in_sizes[1] / 2;
    float* out = (float*)d_out;

    const int total = N + M;
    const int nb    = (total + 255) / 256;

    int nsplit = 64;
    while (nsplit > 1 &&
           (size_t)total * nsplit * 4 + (size_t)nb * 4 > ws_size)
        nsplit >>= 1;

    float* wmin = (float*)d_ws;                       // nsplit * total floats
    float* bsum = wmin + (size_t)total * nsplit;      // nb floats

    const int tA = (N + TILE - 1) / TILE;
    const int tB = (M + TILE - 1) / TILE;
    dim3 g1(tA > tB ? tA : tB, nsplit, 2);
    hipLaunchKernelGGL(chamfer_partial_min, g1, dim3(K1_THREADS), 0, stream,
                       p, N, q, M, nsplit, wmin);

    hipLaunchKernelGGL(chamfer_reduce_points, dim3(nb), dim3(256), 0, stream,
                       wmin, total, nsplit, bsum);
    hipLaunchKernelGGL(chamfer_final, dim3(1), dim3(256), 0, stream, bsum, nb, out);
}

// Round 5
// 44.652 us; speedup vs baseline: 1.2740x; 1.2740x over previous
//
#include <hip/hip_runtime.h>
#include <math.h>

typedef float f32x2 __attribute__((ext_vector_type(2)));

#define K1_THREADS 256
#define R_OUTER    8
#define TILE       (K1_THREADS * R_OUTER)   // 2048 outer points per block
#define MAX_STAGE  1024                     // inner points staged per pass (12 KB LDS)

__device__ __forceinline__ f32x2 pk_fma(f32x2 a, f32x2 b, f32x2 c) {
    f32x2 d;
    asm("v_pk_fma_f32 %0, %1, %2, %3" : "=v"(d) : "v"(a), "v"(b), "v"(c));
    return d;
}
__device__ __forceinline__ float min3f(float a, float b, float c) {
    float d;
    asm("v_min3_f32 %0, %1, %2, %3" : "=v"(d) : "v"(a), "v"(b), "v"(c));
    return d;
}

// min_j |p - q_j|^2 = |p|^2 + min_j (c_j + a_j*px + b_j*py),
// a = -2 qx, b = -2 qy, c = qx^2 + qy^2   (a,b,c staged in LDS SoA).
// Result folded across splits with atomicMin on int-viewed non-negative floats
// (bit order == value order for floats >= 0; min is commutative -> deterministic).
__global__ __launch_bounds__(K1_THREADS) void chamfer_partial_min(
    const float2* __restrict__ p, int n_p,
    const float2* __restrict__ q, int n_q,
    int nsplit, int* __restrict__ ws_min)   // [n_p + n_q] float-as-int
{
    const int side = blockIdx.z;
    const float2* __restrict__ outer = side ? q : p;
    const float2* __restrict__ inner = side ? p : q;
    const int n_outer = side ? n_q : n_p;
    const int n_inner = side ? n_p : n_q;
    int* __restrict__ wbase = ws_min + (side ? n_p : 0);

    const int tile = blockIdx.x;
    if (tile * TILE >= n_outer) return;          // uniform whole-block OOB
    const int split = blockIdx.y;
    const int tid   = threadIdx.x;

    // this split's inner range (chunk multiple of 4; splits may overlap-pad)
    const int chunk = ((n_inner + nsplit - 1) / nsplit + 3) & ~3;
    const int jlo   = split * chunk;

    // load R_OUTER outer points into registers (packed broadcast pairs)
    f32x2 px2[R_OUTER], py2[R_OUTER];
    float m0[R_OUTER], m1[R_OUTER];
    #pragma unroll
    for (int r = 0; r < R_OUTER; ++r) {
        const int idx = tile * TILE + r * K1_THREADS + tid;
        float2 pp = (idx < n_outer) ? outer[idx] : make_float2(0.f, 0.f);
        px2[r] = (f32x2){pp.x, pp.x};
        py2[r] = (f32x2){pp.y, pp.y};
        m0[r]  = 3.0e38f;
        m1[r]  = 3.0e38f;
    }

    __shared__ __align__(16) float sA[MAX_STAGE];
    __shared__ __align__(16) float sB[MAX_STAGE];
    __shared__ __align__(16) float sC[MAX_STAGE];

    for (int base = jlo; base < jlo + chunk; base += MAX_STAGE) {
        const int len = min(MAX_STAGE, jlo + chunk - base);   // multiple of 4

        // stage: 2 points per thread-iteration, float2 LDS writes
        for (int k = tid; k < (len >> 1); k += K1_THREADS) {
            const int pt = base + (k << 1);
            float x0, y0, x1, y1; int v0, v1;
            if (pt + 1 < n_inner) {
                float4 v = *(const float4*)&inner[pt];
                x0 = v.x; y0 = v.y; x1 = v.z; y1 = v.w; v0 = v1 = 1;
            } else if (pt < n_inner) {
                float2 a = inner[pt];
                x0 = a.x; y0 = a.y; x1 = 0.f; y1 = 0.f; v0 = 1; v1 = 0;
            } else {
                x0 = y0 = x1 = y1 = 0.f; v0 = v1 = 0;
            }
            *(float2*)&sA[k << 1] = make_float2(-2.f * x0, -2.f * x1);
            *(float2*)&sB[k << 1] = make_float2(-2.f * y0, -2.f * y1);
            *(float2*)&sC[k << 1] = make_float2(
                v0 ? fmaf(x0, x0, y0 * y0) : 3.0e37f,
                v1 ? fmaf(x1, x1, y1 * y1) : 3.0e37f);
        }
        __syncthreads();

        const int n4 = len >> 2;
        #pragma unroll 2
        for (int k4 = 0; k4 < n4; ++k4) {
            float4 A = ((const float4*)sA)[k4];
            float4 B = ((const float4*)sB)[k4];
            float4 C = ((const float4*)sC)[k4];
            f32x2 alo = (f32x2){A.x, A.y}, ahi = (f32x2){A.z, A.w};
            f32x2 blo = (f32x2){B.x, B.y}, bhi = (f32x2){B.z, B.w};
            f32x2 clo = (f32x2){C.x, C.y}, chi = (f32x2){C.z, C.w};
            #pragma unroll
            for (int r = 0; r < R_OUTER; ++r) {
                f32x2 t0 = pk_fma(blo, py2[r], clo);
                t0 = pk_fma(alo, px2[r], t0);
                f32x2 t1 = pk_fma(bhi, py2[r], chi);
                t1 = pk_fma(ahi, px2[r], t1);
                m0[r] = min3f(m0[r], t0.x, t0.y);
                m1[r] = min3f(m1[r], t1.x, t1.y);
            }
        }
        __syncthreads();
    }

    // epilogue: add |p|^2, fold across splits via atomicMin on int-viewed float
    #pragma unroll
    for (int r = 0; r < R_OUTER; ++r) {
        const int idx = tile * TILE + r * K1_THREADS + tid;
        if (idx < n_outer) {
            const float px = px2[r].x, py = py2[r].x;
            const float hp = fmaf(px, px, py * py);
            const float v  = fminf(m0[r], m1[r]) + hp;
            atomicMin(&wbase[idx], __float_as_int(v));   // v >= 0 always
        }
    }
}

// per-point sqrt + block partial sums (ws holds min d^2 as int-viewed float)
__global__ __launch_bounds__(256) void chamfer_reduce_points(
    const int* __restrict__ ws_min, int total_pts,
    float* __restrict__ block_sums)
{
    const int i = blockIdx.x * 256 + threadIdx.x;
    float d = 0.f;
    if (i < total_pts) {
        float mv = __int_as_float(ws_min[i]);
        d = sqrtf(fmaxf(mv, 0.f));
    }
    #pragma unroll
    for (int off = 32; off > 0; off >>= 1) d += __shfl_down(d, off);
    __shared__ float s[4];
    if ((threadIdx.x & 63) == 0) s[threadIdx.x >> 6] = d;
    __syncthreads();
    if (threadIdx.x == 0) block_sums[blockIdx.x] = (s[0] + s[1]) + (s[2] + s[3]);
}

__global__ __launch_bounds__(256) void chamfer_final(
    const float* __restrict__ block_sums, int n, float* __restrict__ out)
{
    float d = 0.f;
    for (int k = threadIdx.x; k < n; k += 256) d += block_sums[k];
    #pragma unroll
    for (int off = 32; off > 0; off >>= 1) d += __shfl_down(d, off);
    __shared__ float s[4];
    if ((threadIdx.x & 63) == 0) s[threadIdx.x >> 6] = d;
    __syncthreads();
    if (threadIdx.x == 0) out[0] = (s[0] + s[1]) + (s[2] + s[3]);
}

extern "C" void kernel_launch(void* const* d_in, const int* in_sizes, int n_in,
                              void* d_out, int out_size, void* d_ws, size_t ws_size,
                              hipStream_t stream) {
    const float2* p = (const float2*)d_in[0];   // (16384, 2) f32
    const float2* q = (const float2*)d_in[1];   // (16384, 2) f32
    const int N = in_sizes[0] / 2;
    const int M = in_sizes[1] / 2;
    float* out = (float*)d_out;

    const int total = N + M;
    const int nb    = (total + 255) / 256;

    int*   wmin = (int*)d_ws;                   // total ints (float bits)
    float* bsum = (float*)d_ws + total;         // nb floats

    // init per-point mins to +huge (0x7F7F7F7F == 3.39e38f): bitwise memset
    hipMemsetAsync(wmin, 0x7F, (size_t)total * sizeof(int), stream);

    const int nsplit = 64;
    const int tA = (N + TILE - 1) / TILE;
    const int tB = (M + TILE - 1) / TILE;
    dim3 g1(tA > tB ? tA : tB, nsplit, 2);
    hipLaunchKernelGGL(chamfer_partial_min, g1, dim3(K1_THREADS), 0, stream,
                       p, N, q, M, nsplit, wmin);

    hipLaunchKernelGGL(chamfer_reduce_points, dim3(nb), dim3(256), 0, stream,
                       wmin, total, bsum);
    hipLaunchKernelGGL(chamfer_final, dim3(1), dim3(256), 0, stream, bsum, nb, out);
}